// Round 1
// baseline (3952.917 us; speedup 1.0000x reference)
//
#include <hip/hip_runtime.h>

#define BLOCK 256
#define DDIM 64

// cur[row, :] += scale[row] * emb0[row, :]   (vectorized float4, 16 float4 per row)
__global__ void add_scaled4(float4* __restrict__ cur, const float4* __restrict__ emb0,
                            const float* __restrict__ scale, long n4) {
    long idx = blockIdx.x * (long)blockDim.x + threadIdx.x;
    long stride = (long)gridDim.x * blockDim.x;
    for (; idx < n4; idx += stride) {
        float s = scale[idx >> 4];          // 64/4 = 16 float4 per row
        float4 e = emb0[idx];
        float4 c = cur[idx];
        c.x += s * e.x; c.y += s * e.y; c.z += s * e.z; c.w += s * e.w;
        cur[idx] = c;
    }
}

// out[rows[e], d] += vals[e] * x[cols[e], d]   one thread per (edge, dim)
__global__ void spmm_push(const int* __restrict__ rows, const int* __restrict__ cols,
                          const float* __restrict__ vals, const float* __restrict__ x,
                          float* __restrict__ out, long nnz) {
    long idx = blockIdx.x * (long)blockDim.x + threadIdx.x;
    long stride = (long)gridDim.x * blockDim.x;
    long total = nnz << 6;
    for (; idx < total; idx += stride) {
        long e = idx >> 6;
        int d = (int)(idx & 63);
        int r = rows[e];
        int c = cols[e];
        float v = vals[e];
        atomicAdd(&out[(long)r * DDIM + d], v * x[(long)c * DDIM + d]);
    }
}

// acc[b, d] += emb[idxs[b], d]
__global__ void gather_add(float* __restrict__ acc, const float* __restrict__ emb,
                           const int* __restrict__ idxs, int batch) {
    int t = blockIdx.x * blockDim.x + threadIdx.x;
    if (t >= batch * DDIM) return;
    int b = t >> 6;
    acc[t] += emb[(long)idxs[b] * DDIM + (t & 63)];
}

// gamma[b] = (1/16) * sum_d uacc[b,d]*iacc[b,d]
__global__ void final_gamma(const float* __restrict__ uacc, const float* __restrict__ iacc,
                            float* __restrict__ out, int batch) {
    int t = blockIdx.x * blockDim.x + threadIdx.x;
    if (t >= batch * DDIM) return;
    int b = t >> 6;
    float v = uacc[t] * iacc[t];
    #pragma unroll
    for (int off = 32; off; off >>= 1) v += __shfl_down(v, off, 64);
    if ((threadIdx.x & 63) == 0) out[b] = v * (1.0f / 16.0f);
}

static inline int nblk(long threads, long cap) {
    long b = (threads + BLOCK - 1) / BLOCK;
    if (b > cap) b = cap;
    if (b < 1) b = 1;
    return (int)b;
}

extern "C" void kernel_launch(void* const* d_in, const int* in_sizes, int n_in,
                              void* d_out, int out_size, void* d_ws, size_t ws_size,
                              hipStream_t stream) {
    const float* user_emb = (const float*)d_in[0];
    const float* item_emb = (const float*)d_in[1];
    const float* du       = (const float*)d_in[2];
    const float* dv       = (const float*)d_in[3];
    const float* ui_vals  = (const float*)d_in[4];
    const float* uu_vals  = (const float*)d_in[5];
    const float* vv_vals  = (const float*)d_in[6];
    const int*   ui_rows  = (const int*)d_in[7];
    const int*   ui_cols  = (const int*)d_in[8];
    const int*   uu_rows  = (const int*)d_in[9];
    const int*   uu_cols  = (const int*)d_in[10];
    const int*   vv_rows  = (const int*)d_in[11];
    const int*   vv_cols  = (const int*)d_in[12];
    const int*   users    = (const int*)d_in[13];
    const int*   items    = (const int*)d_in[14];

    const int U = in_sizes[2];           // du is [U,1]
    const int I = in_sizes[3];           // dv is [I,1]
    const long nnz_ui = in_sizes[4];
    const long nnz_uu = in_sizes[5];
    const long nnz_vv = in_sizes[6];
    const int batch = in_sizes[13];

    const long UD = (long)U * DDIM;
    const long ID = (long)I * DDIM;

    float* ws = (float*)d_ws;
    float* uA   = ws;                 // [U,64]
    float* uB   = uA + UD;            // [U,64]
    float* iA   = uB + UD;            // [I,64]
    float* iB   = iA + ID;            // [I,64]
    float* uacc = iB + ID;            // [batch,64]
    float* iacc = uacc + (long)batch * DDIM;

    float* gamma = (float*)d_out;

    // --- init: cur = emb0, acc = emb0[sampled] (layer-0 term) ---
    hipMemcpyAsync(uA, user_emb, UD * sizeof(float), hipMemcpyDeviceToDevice, stream);
    hipMemcpyAsync(iA, item_emb, ID * sizeof(float), hipMemcpyDeviceToDevice, stream);
    hipMemsetAsync(uacc, 0, (size_t)batch * DDIM * sizeof(float), stream);
    hipMemsetAsync(iacc, 0, (size_t)batch * DDIM * sizeof(float), stream);

    int gb = (batch * DDIM + BLOCK - 1) / BLOCK;
    gather_add<<<gb, BLOCK, 0, stream>>>(uacc, uA, users, batch);
    gather_add<<<gb, BLOCK, 0, stream>>>(iacc, iA, items, batch);

    float* ucur = uA; float* unext = uB;
    float* icur = iA; float* inext = iB;

    for (int layer = 0; layer < 3; ++layer) {
        // cur += d * emb0
        add_scaled4<<<nblk(UD / 4, 4096), BLOCK, 0, stream>>>(
            (float4*)ucur, (const float4*)user_emb, du, UD / 4);
        add_scaled4<<<nblk(ID / 4, 4096), BLOCK, 0, stream>>>(
            (float4*)icur, (const float4*)item_emb, dv, ID / 4);

        // users_next = A_ui @ icur + A_uu @ ucur
        hipMemsetAsync(unext, 0, UD * sizeof(float), stream);
        spmm_push<<<nblk(nnz_ui << 6, 16384), BLOCK, 0, stream>>>(
            ui_rows, ui_cols, ui_vals, icur, unext, nnz_ui);
        spmm_push<<<nblk(nnz_uu << 6, 16384), BLOCK, 0, stream>>>(
            uu_rows, uu_cols, uu_vals, ucur, unext, nnz_uu);

        // items_next = A_vv @ icur + A_ui^T @ unext   (uses NEW users)
        hipMemsetAsync(inext, 0, ID * sizeof(float), stream);
        spmm_push<<<nblk(nnz_vv << 6, 16384), BLOCK, 0, stream>>>(
            vv_rows, vv_cols, vv_vals, icur, inext, nnz_vv);
        spmm_push<<<nblk(nnz_ui << 6, 16384), BLOCK, 0, stream>>>(
            ui_cols, ui_rows, ui_vals, unext, inext, nnz_ui);  // transpose edges

        // acc += next[sampled]
        gather_add<<<gb, BLOCK, 0, stream>>>(uacc, unext, users, batch);
        gather_add<<<gb, BLOCK, 0, stream>>>(iacc, inext, items, batch);

        // swap ping-pong
        float* t;
        t = ucur; ucur = unext; unext = t;
        t = icur; icur = inext; inext = t;
    }

    // gamma = (1/16) * <uacc[b,:], iacc[b,:]>
    final_gamma<<<gb, BLOCK, 0, stream>>>(uacc, iacc, gamma, batch);
}

// Round 2
// 1642.988 us; speedup vs baseline: 2.4059x; 2.4059x over previous
//
#include <hip/hip_runtime.h>

#define BLOCK 256
#define DDIM 64
#define SCAN_CHUNK 2048   // 256 threads * 8 elements

// ---------- elementwise / small kernels ----------

__global__ void add_scaled4(float4* __restrict__ cur, const float4* __restrict__ emb0,
                            const float* __restrict__ scale, long n4) {
    long idx = blockIdx.x * (long)blockDim.x + threadIdx.x;
    long stride = (long)gridDim.x * blockDim.x;
    for (; idx < n4; idx += stride) {
        float s = scale[idx >> 4];
        float4 e = emb0[idx];
        float4 c = cur[idx];
        c.x += s * e.x; c.y += s * e.y; c.z += s * e.z; c.w += s * e.w;
        cur[idx] = c;
    }
}

__global__ void gather_add(float* __restrict__ acc, const float* __restrict__ emb,
                           const int* __restrict__ idxs, int batch) {
    int t = blockIdx.x * blockDim.x + threadIdx.x;
    if (t >= batch * DDIM) return;
    int b = t >> 6;
    acc[t] += emb[(long)idxs[b] * DDIM + (t & 63)];
}

__global__ void final_gamma(const float* __restrict__ uacc, const float* __restrict__ iacc,
                            float* __restrict__ out, int batch) {
    int t = blockIdx.x * blockDim.x + threadIdx.x;
    if (t >= batch * DDIM) return;
    int b = t >> 6;
    float v = uacc[t] * iacc[t];
    #pragma unroll
    for (int off = 32; off; off >>= 1) v += __shfl_down(v, off, 64);
    if ((threadIdx.x & 63) == 0) out[b] = v * (1.0f / 16.0f);
}

// ---------- CSR build ----------

__global__ void hist_kernel(const int* __restrict__ rows, long nnz, int* __restrict__ cnt) {
    long idx = blockIdx.x * (long)blockDim.x + threadIdx.x;
    long stride = (long)gridDim.x * blockDim.x;
    for (; idx < nnz; idx += stride) atomicAdd(&cnt[rows[idx]], 1);
}

__global__ void block_sums(const int* __restrict__ in, int n, int* __restrict__ bsum) {
    __shared__ int sdata[256];
    int base = blockIdx.x * SCAN_CHUNK;
    int t = threadIdx.x;
    int s = 0;
    #pragma unroll
    for (int k = 0; k < 8; ++k) {
        int i = base + t * 8 + k;
        if (i < n) s += in[i];
    }
    sdata[t] = s;
    __syncthreads();
    for (int off = 128; off; off >>= 1) {
        if (t < off) sdata[t] += sdata[t + off];
        __syncthreads();
    }
    if (t == 0) bsum[blockIdx.x] = sdata[0];
}

// single block: exclusive-scan bsum[0..nb) in place; write grand total to *total_out
__global__ void scan_bsums(int* __restrict__ bsum, int nb, int* __restrict__ total_out) {
    __shared__ int sdata[256];
    int t = threadIdx.x;
    int v = (t < nb) ? bsum[t] : 0;
    sdata[t] = v;
    __syncthreads();
    for (int off = 1; off < 256; off <<= 1) {
        int add = (t >= off) ? sdata[t - off] : 0;
        __syncthreads();
        sdata[t] += add;
        __syncthreads();
    }
    if (t < nb) bsum[t] = sdata[t] - v;   // exclusive
    if (t == 255) *total_out = sdata[255];
}

__global__ void scan_chunks(const int* __restrict__ in, int n, const int* __restrict__ bsum,
                            int* __restrict__ out /* exclusive row_ptr[0..n) */) {
    __shared__ int sdata[256];
    int base = blockIdx.x * SCAN_CHUNK;
    int t = threadIdx.x;
    int loc[8];
    int s = 0;
    #pragma unroll
    for (int k = 0; k < 8; ++k) {
        int i = base + t * 8 + k;
        int v = (i < n) ? in[i] : 0;
        loc[k] = s;
        s += v;
    }
    sdata[t] = s;
    __syncthreads();
    for (int off = 1; off < 256; off <<= 1) {
        int add = (t >= off) ? sdata[t - off] : 0;
        __syncthreads();
        sdata[t] += add;
        __syncthreads();
    }
    int texcl = sdata[t] - s + bsum[blockIdx.x];
    #pragma unroll
    for (int k = 0; k < 8; ++k) {
        int i = base + t * 8 + k;
        if (i < n) out[i] = texcl + loc[k];
    }
}

__global__ void scatter_csr(const int* __restrict__ rows, const int* __restrict__ cols,
                            const float* __restrict__ vals, const int* __restrict__ rp,
                            int* __restrict__ cur, int* __restrict__ cc, float* __restrict__ cv,
                            long nnz) {
    long idx = blockIdx.x * (long)blockDim.x + threadIdx.x;
    long stride = (long)gridDim.x * blockDim.x;
    for (; idx < nnz; idx += stride) {
        int r = rows[idx];
        int pos = rp[r] + atomicAdd(&cur[r], 1);
        cc[pos] = cols[idx];
        cv[pos] = vals[idx];
    }
}

// ---------- pull-style fused SpMM: out[r,:] = sum_A vA*xA[cA] + sum_B vB*xB[cB] ----------

__global__ void pull2(const int* __restrict__ rpA, const int* __restrict__ cA,
                      const float* __restrict__ vA, const float* __restrict__ xA,
                      const int* __restrict__ rpB, const int* __restrict__ cB,
                      const float* __restrict__ vB, const float* __restrict__ xB,
                      float* __restrict__ out, int nrows) {
    int wave = (int)((blockIdx.x * (long)blockDim.x + threadIdx.x) >> 6);
    int lane = threadIdx.x & 63;
    if (wave >= nrows) return;
    float acc = 0.0f;

    #pragma unroll
    for (int g = 0; g < 2; ++g) {
        const int* rp = g ? rpB : rpA;
        const int* cc = g ? cB : cA;
        const float* vv = g ? vB : vA;
        const float* x = g ? xB : xA;
        int s = rp[wave], e = rp[wave + 1];
        for (int j = s; j < e; j += 64) {
            int cnt = e - j; if (cnt > 64) cnt = 64;
            int myc = 0; float myv = 0.0f;
            if (lane < cnt) { myc = cc[j + lane]; myv = vv[j + lane]; }
            int t = 0;
            for (; t + 4 <= cnt; t += 4) {
                int c0 = __shfl(myc, t, 64);
                int c1 = __shfl(myc, t + 1, 64);
                int c2 = __shfl(myc, t + 2, 64);
                int c3 = __shfl(myc, t + 3, 64);
                float w0 = __shfl(myv, t, 64);
                float w1 = __shfl(myv, t + 1, 64);
                float w2 = __shfl(myv, t + 2, 64);
                float w3 = __shfl(myv, t + 3, 64);
                float x0 = x[(long)c0 * DDIM + lane];
                float x1 = x[(long)c1 * DDIM + lane];
                float x2 = x[(long)c2 * DDIM + lane];
                float x3 = x[(long)c3 * DDIM + lane];
                acc += w0 * x0; acc += w1 * x1; acc += w2 * x2; acc += w3 * x3;
            }
            for (; t < cnt; ++t) {
                int c = __shfl(myc, t, 64);
                float w = __shfl(myv, t, 64);
                acc += w * x[(long)c * DDIM + lane];
            }
        }
    }
    out[(long)wave * DDIM + lane] = acc;
}

// ---------- legacy push path (fallback if ws too small) ----------

__global__ void spmm_push(const int* __restrict__ rows, const int* __restrict__ cols,
                          const float* __restrict__ vals, const float* __restrict__ x,
                          float* __restrict__ out, long nnz) {
    long idx = blockIdx.x * (long)blockDim.x + threadIdx.x;
    long stride = (long)gridDim.x * blockDim.x;
    long total = nnz << 6;
    for (; idx < total; idx += stride) {
        long e = idx >> 6;
        int d = (int)(idx & 63);
        int r = rows[e];
        int c = cols[e];
        float v = vals[e];
        atomicAdd(&out[(long)r * DDIM + d], v * x[(long)c * DDIM + d]);
    }
}

static inline int nblk(long threads, long cap) {
    long b = (threads + BLOCK - 1) / BLOCK;
    if (b > cap) b = cap;
    if (b < 1) b = 1;
    return (int)b;
}

static void build_csr(const int* rows, const int* cols, const float* vals, long nnz,
                      int n, int* rp, int* cnt, int* bsum, int* cc, float* cv,
                      hipStream_t stream) {
    int nb = (n + SCAN_CHUNK - 1) / SCAN_CHUNK;   // <= 256 for n <= 524288
    hipMemsetAsync(cnt, 0, (size_t)n * sizeof(int), stream);
    hist_kernel<<<nblk(nnz, 2048), BLOCK, 0, stream>>>(rows, nnz, cnt);
    block_sums<<<nb, 256, 0, stream>>>(cnt, n, bsum);
    scan_bsums<<<1, 256, 0, stream>>>(bsum, nb, rp + n);   // writes rp[n] = nnz
    scan_chunks<<<nb, 256, 0, stream>>>(cnt, n, bsum, rp);
    hipMemsetAsync(cnt, 0, (size_t)n * sizeof(int), stream);
    scatter_csr<<<nblk(nnz, 2048), BLOCK, 0, stream>>>(rows, cols, vals, rp, cnt, cc, cv, nnz);
}

extern "C" void kernel_launch(void* const* d_in, const int* in_sizes, int n_in,
                              void* d_out, int out_size, void* d_ws, size_t ws_size,
                              hipStream_t stream) {
    const float* user_emb = (const float*)d_in[0];
    const float* item_emb = (const float*)d_in[1];
    const float* du       = (const float*)d_in[2];
    const float* dv       = (const float*)d_in[3];
    const float* ui_vals  = (const float*)d_in[4];
    const float* uu_vals  = (const float*)d_in[5];
    const float* vv_vals  = (const float*)d_in[6];
    const int*   ui_rows  = (const int*)d_in[7];
    const int*   ui_cols  = (const int*)d_in[8];
    const int*   uu_rows  = (const int*)d_in[9];
    const int*   uu_cols  = (const int*)d_in[10];
    const int*   vv_rows  = (const int*)d_in[11];
    const int*   vv_cols  = (const int*)d_in[12];
    const int*   users    = (const int*)d_in[13];
    const int*   items    = (const int*)d_in[14];

    const int U = in_sizes[2];
    const int I = in_sizes[3];
    const long nnz_ui = in_sizes[4];
    const long nnz_uu = in_sizes[5];
    const long nnz_vv = in_sizes[6];
    const int batch = in_sizes[13];

    const long UD = (long)U * DDIM;
    const long ID = (long)I * DDIM;

    float* gamma = (float*)d_out;

    // ---- workspace carve-up ----
    char* p = (char*)d_ws;
    size_t need = 0;
    #define CARVE(ptr, type, count) type* ptr = (type*)(p + need); need += ((size_t)(count) * sizeof(type) + 255) & ~(size_t)255;
    CARVE(uA, float, UD)
    CARVE(uB, float, UD)
    CARVE(iA, float, ID)
    CARVE(iB, float, ID)
    CARVE(uacc, float, (long)batch * DDIM)
    CARVE(iacc, float, (long)batch * DDIM)
    CARVE(rp_ui, int, U + 1)
    CARVE(rp_uiT, int, I + 1)
    CARVE(rp_uu, int, U + 1)
    CARVE(rp_vv, int, I + 1)
    CARVE(cnt_u, int, U)
    CARVE(cnt_i, int, I)
    CARVE(bsum, int, 4096)
    CARVE(ui_cc, int, nnz_ui)
    CARVE(ui_cv, float, nnz_ui)
    CARVE(uiT_cc, int, nnz_ui)
    CARVE(uiT_cv, float, nnz_ui)
    CARVE(uu_cc, int, nnz_uu)
    CARVE(uu_cv, float, nnz_uu)
    CARVE(vv_cc, int, nnz_vv)
    CARVE(vv_cv, float, nnz_vv)
    #undef CARVE

    int gb = (batch * DDIM + BLOCK - 1) / BLOCK;

    if (need <= ws_size) {
        // ================= CSR pull path =================
        build_csr(ui_rows, ui_cols, ui_vals, nnz_ui, U, rp_ui, cnt_u, bsum, ui_cc, ui_cv, stream);
        build_csr(ui_cols, ui_rows, ui_vals, nnz_ui, I, rp_uiT, cnt_i, bsum, uiT_cc, uiT_cv, stream);
        build_csr(uu_rows, uu_cols, uu_vals, nnz_uu, U, rp_uu, cnt_u, bsum, uu_cc, uu_cv, stream);
        build_csr(vv_rows, vv_cols, vv_vals, nnz_vv, I, rp_vv, cnt_i, bsum, vv_cc, vv_cv, stream);

        hipMemcpyAsync(uA, user_emb, UD * sizeof(float), hipMemcpyDeviceToDevice, stream);
        hipMemcpyAsync(iA, item_emb, ID * sizeof(float), hipMemcpyDeviceToDevice, stream);
        hipMemsetAsync(uacc, 0, (size_t)batch * DDIM * sizeof(float), stream);
        hipMemsetAsync(iacc, 0, (size_t)batch * DDIM * sizeof(float), stream);

        gather_add<<<gb, BLOCK, 0, stream>>>(uacc, uA, users, batch);
        gather_add<<<gb, BLOCK, 0, stream>>>(iacc, iA, items, batch);

        float* ucur = uA; float* unext = uB;
        float* icur = iA; float* inext = iB;

        int ub = (U * 64 + BLOCK - 1) / BLOCK;   // one wave per row, 4 rows/block
        int ib = (I * 64 + BLOCK - 1) / BLOCK;

        for (int layer = 0; layer < 3; ++layer) {
            add_scaled4<<<nblk(UD / 4, 4096), BLOCK, 0, stream>>>(
                (float4*)ucur, (const float4*)user_emb, du, UD / 4);
            add_scaled4<<<nblk(ID / 4, 4096), BLOCK, 0, stream>>>(
                (float4*)icur, (const float4*)item_emb, dv, ID / 4);

            // users_next = A_ui @ icur + A_uu @ ucur   (written once, no memset)
            pull2<<<ub, BLOCK, 0, stream>>>(rp_ui, ui_cc, ui_cv, icur,
                                            rp_uu, uu_cc, uu_cv, ucur, unext, U);
            // items_next = A_ui^T @ unext + A_vv @ icur
            pull2<<<ib, BLOCK, 0, stream>>>(rp_uiT, uiT_cc, uiT_cv, unext,
                                            rp_vv, vv_cc, vv_cv, icur, inext, I);

            gather_add<<<gb, BLOCK, 0, stream>>>(uacc, unext, users, batch);
            gather_add<<<gb, BLOCK, 0, stream>>>(iacc, inext, items, batch);

            float* t;
            t = ucur; ucur = unext; unext = t;
            t = icur; icur = inext; inext = t;
        }

        final_gamma<<<gb, BLOCK, 0, stream>>>(uacc, iacc, gamma, batch);
    } else {
        // ================= fallback: push-atomic path (round-1, proven) =================
        float* ws = (float*)d_ws;
        float* fuA   = ws;
        float* fuB   = fuA + UD;
        float* fiA   = fuB + UD;
        float* fiB   = fiA + ID;
        float* fuacc = fiB + ID;
        float* fiacc = fuacc + (long)batch * DDIM;

        hipMemcpyAsync(fuA, user_emb, UD * sizeof(float), hipMemcpyDeviceToDevice, stream);
        hipMemcpyAsync(fiA, item_emb, ID * sizeof(float), hipMemcpyDeviceToDevice, stream);
        hipMemsetAsync(fuacc, 0, (size_t)batch * DDIM * sizeof(float), stream);
        hipMemsetAsync(fiacc, 0, (size_t)batch * DDIM * sizeof(float), stream);

        gather_add<<<gb, BLOCK, 0, stream>>>(fuacc, fuA, users, batch);
        gather_add<<<gb, BLOCK, 0, stream>>>(fiacc, fiA, items, batch);

        float* ucur = fuA; float* unext = fuB;
        float* icur = fiA; float* inext = fiB;

        for (int layer = 0; layer < 3; ++layer) {
            add_scaled4<<<nblk(UD / 4, 4096), BLOCK, 0, stream>>>(
                (float4*)ucur, (const float4*)user_emb, du, UD / 4);
            add_scaled4<<<nblk(ID / 4, 4096), BLOCK, 0, stream>>>(
                (float4*)icur, (const float4*)item_emb, dv, ID / 4);

            hipMemsetAsync(unext, 0, UD * sizeof(float), stream);
            spmm_push<<<nblk(nnz_ui << 6, 16384), BLOCK, 0, stream>>>(
                ui_rows, ui_cols, ui_vals, icur, unext, nnz_ui);
            spmm_push<<<nblk(nnz_uu << 6, 16384), BLOCK, 0, stream>>>(
                uu_rows, uu_cols, uu_vals, ucur, unext, nnz_uu);

            hipMemsetAsync(inext, 0, ID * sizeof(float), stream);
            spmm_push<<<nblk(nnz_vv << 6, 16384), BLOCK, 0, stream>>>(
                vv_rows, vv_cols, vv_vals, icur, inext, nnz_vv);
            spmm_push<<<nblk(nnz_ui << 6, 16384), BLOCK, 0, stream>>>(
                ui_cols, ui_rows, ui_vals, unext, inext, nnz_ui);

            gather_add<<<gb, BLOCK, 0, stream>>>(fuacc, unext, users, batch);
            gather_add<<<gb, BLOCK, 0, stream>>>(fiacc, inext, items, batch);

            float* t;
            t = ucur; ucur = unext; unext = t;
            t = icur; icur = inext; inext = t;
        }

        final_gamma<<<gb, BLOCK, 0, stream>>>(fuacc, fiacc, gamma, batch);
    }
}

// Round 3
// 1325.260 us; speedup vs baseline: 2.9827x; 1.2397x over previous
//
#include <hip/hip_runtime.h>

#define BLOCK 256
#define DDIM 64
#define SCAN_CHUNK 2048   // 256 threads * 8 elements
#define NBMAX 128         // max scan chunks per segment (U=200K -> 98)

// ---------- elementwise / small kernels ----------

// dst = emb0 * (1 + scale[row])   (layer-0 fused copy+add)
__global__ void first_comb4(float4* __restrict__ dst, const float4* __restrict__ emb0,
                            const float* __restrict__ scale, long n4) {
    long idx = blockIdx.x * (long)blockDim.x + threadIdx.x;
    long stride = (long)gridDim.x * blockDim.x;
    for (; idx < n4; idx += stride) {
        float s = 1.0f + scale[idx >> 4];
        float4 e = emb0[idx];
        e.x *= s; e.y *= s; e.z *= s; e.w *= s;
        dst[idx] = e;
    }
}

// cur += scale[row] * emb0
__global__ void add_scaled4(float4* __restrict__ cur, const float4* __restrict__ emb0,
                            const float* __restrict__ scale, long n4) {
    long idx = blockIdx.x * (long)blockDim.x + threadIdx.x;
    long stride = (long)gridDim.x * blockDim.x;
    for (; idx < n4; idx += stride) {
        float s = scale[idx >> 4];
        float4 e = emb0[idx];
        float4 c = cur[idx];
        c.x += s * e.x; c.y += s * e.y; c.z += s * e.z; c.w += s * e.w;
        cur[idx] = c;
    }
}

__global__ void gather_add(float* __restrict__ acc, const float* __restrict__ emb,
                           const int* __restrict__ idxs, int batch) {
    int t = blockIdx.x * blockDim.x + threadIdx.x;
    if (t >= batch * DDIM) return;
    int b = t >> 6;
    acc[t] += emb[(long)idxs[b] * DDIM + (t & 63)];
}

__global__ void final_gamma(const float* __restrict__ uacc, const float* __restrict__ iacc,
                            float* __restrict__ out, int batch) {
    int t = blockIdx.x * blockDim.x + threadIdx.x;
    if (t >= batch * DDIM) return;
    int b = t >> 6;
    float v = uacc[t] * iacc[t];
    #pragma unroll
    for (int off = 32; off; off >>= 1) v += __shfl_down(v, off, 64);
    if ((threadIdx.x & 63) == 0) out[b] = v * (1.0f / 16.0f);
}

// ---------- CSR build (fused) ----------

// 4 histograms in one kernel
__global__ void hist4(const int* __restrict__ a0, long n0, int* __restrict__ c0,
                      const int* __restrict__ a1, long n1, int* __restrict__ c1,
                      const int* __restrict__ a2, long n2, int* __restrict__ c2,
                      const int* __restrict__ a3, long n3, int* __restrict__ c3) {
    long idx = blockIdx.x * (long)blockDim.x + threadIdx.x;
    long stride = (long)gridDim.x * blockDim.x;
    long t01 = n0 + n1, t012 = n0 + n1 + n2, total = t012 + n3;
    for (; idx < total; idx += stride) {
        if (idx < n0)        atomicAdd(&c0[a0[idx]], 1);
        else if (idx < t01)  atomicAdd(&c1[a1[idx - n0]], 1);
        else if (idx < t012) atomicAdd(&c2[a2[idx - t01]], 1);
        else                 atomicAdd(&c3[a3[idx - t012]], 1);
    }
}

// segmented block sums over 4 count arrays
__global__ void block_sums4(const int* __restrict__ i0, int n0, int nb0,
                            const int* __restrict__ i1, int n1, int nb1,
                            const int* __restrict__ i2, int n2, int nb2,
                            const int* __restrict__ i3, int n3, int nb3,
                            int* __restrict__ bsum /* [4][NBMAX] */) {
    __shared__ int sdata[256];
    int b = blockIdx.x, seg, lb; const int* in; int n;
    if (b < nb0)                 { seg = 0; lb = b;                 in = i0; n = n0; }
    else if (b < nb0 + nb1)      { seg = 1; lb = b - nb0;           in = i1; n = n1; }
    else if (b < nb0 + nb1 + nb2){ seg = 2; lb = b - nb0 - nb1;     in = i2; n = n2; }
    else                         { seg = 3; lb = b - nb0 - nb1 - nb2; in = i3; n = n3; }
    int base = lb * SCAN_CHUNK;
    int t = threadIdx.x;
    int s = 0;
    #pragma unroll
    for (int k = 0; k < 8; ++k) {
        int i = base + t * 8 + k;
        if (i < n) s += in[i];
    }
    sdata[t] = s;
    __syncthreads();
    for (int off = 128; off; off >>= 1) {
        if (t < off) sdata[t] += sdata[t + off];
        __syncthreads();
    }
    if (t == 0) bsum[seg * NBMAX + lb] = sdata[0];
}

// 4 blocks; block `seg` exclusive-scans bsum[seg][0..nb) in place, total -> rp[n]
__global__ void scan_bsums4(int* __restrict__ bsum,
                            int nb0, int nb1, int nb2, int nb3,
                            int* __restrict__ rp0, int m0, int* __restrict__ rp1, int m1,
                            int* __restrict__ rp2, int m2, int* __restrict__ rp3, int m3) {
    __shared__ int sdata[NBMAX];
    int seg = blockIdx.x;
    int nb = seg == 0 ? nb0 : seg == 1 ? nb1 : seg == 2 ? nb2 : nb3;
    int* rp = seg == 0 ? rp0 : seg == 1 ? rp1 : seg == 2 ? rp2 : rp3;
    int m  = seg == 0 ? m0  : seg == 1 ? m1  : seg == 2 ? m2  : m3;
    int t = threadIdx.x;                 // blockDim == NBMAX
    int v = (t < nb) ? bsum[seg * NBMAX + t] : 0;
    sdata[t] = v;
    __syncthreads();
    for (int off = 1; off < NBMAX; off <<= 1) {
        int add = (t >= off) ? sdata[t - off] : 0;
        __syncthreads();
        sdata[t] += add;
        __syncthreads();
    }
    if (t < nb) bsum[seg * NBMAX + t] = sdata[t] - v;     // exclusive
    if (t == NBMAX - 1) rp[m] = sdata[NBMAX - 1];         // grand total = nnz
}

// segmented chunk scan: rp[i] = exclusive scan of cnt
__global__ void scan_chunks4(const int* __restrict__ i0, int n0, int nb0, int* __restrict__ r0,
                             const int* __restrict__ i1, int n1, int nb1, int* __restrict__ r1,
                             const int* __restrict__ i2, int n2, int nb2, int* __restrict__ r2,
                             const int* __restrict__ i3, int n3, int nb3, int* __restrict__ r3,
                             const int* __restrict__ bsum) {
    __shared__ int sdata[256];
    int b = blockIdx.x, seg, lb; const int* in; int n; int* out;
    if (b < nb0)                 { seg = 0; lb = b;                 in = i0; n = n0; out = r0; }
    else if (b < nb0 + nb1)      { seg = 1; lb = b - nb0;           in = i1; n = n1; out = r1; }
    else if (b < nb0 + nb1 + nb2){ seg = 2; lb = b - nb0 - nb1;     in = i2; n = n2; out = r2; }
    else                         { seg = 3; lb = b - nb0 - nb1 - nb2; in = i3; n = n3; out = r3; }
    int base = lb * SCAN_CHUNK;
    int t = threadIdx.x;
    int loc[8];
    int s = 0;
    #pragma unroll
    for (int k = 0; k < 8; ++k) {
        int i = base + t * 8 + k;
        int v = (i < n) ? in[i] : 0;
        loc[k] = s;
        s += v;
    }
    sdata[t] = s;
    __syncthreads();
    for (int off = 1; off < 256; off <<= 1) {
        int add = (t >= off) ? sdata[t - off] : 0;
        __syncthreads();
        sdata[t] += add;
        __syncthreads();
    }
    int texcl = sdata[t] - s + bsum[seg * NBMAX + lb];
    #pragma unroll
    for (int k = 0; k < 8; ++k) {
        int i = base + t * 8 + k;
        if (i < n) out[i] = texcl + loc[k];
    }
}

// scatter edges into packed (col,val) CSR; optionally also the transpose
__global__ void scatter_dual(const int* __restrict__ rows, const int* __restrict__ cols,
                             const float* __restrict__ vals,
                             const int* __restrict__ rpA, int* __restrict__ curA, int2* __restrict__ eA,
                             const int* __restrict__ rpB, int* __restrict__ curB, int2* __restrict__ eB,
                             long nnz) {
    long idx = blockIdx.x * (long)blockDim.x + threadIdx.x;
    long stride = (long)gridDim.x * blockDim.x;
    for (; idx < nnz; idx += stride) {
        int r = rows[idx];
        int c = cols[idx];
        int vb = __float_as_int(vals[idx]);
        int pa = rpA[r] + atomicAdd(&curA[r], 1);
        eA[pa] = make_int2(c, vb);
        if (eB) {
            int pb = rpB[c] + atomicAdd(&curB[c], 1);
            eB[pb] = make_int2(r, vb);
        }
    }
}

// ---------- pull-style fused SpMM (packed edges) ----------

__global__ void pull2(const int* __restrict__ rpA, const int2* __restrict__ eA, const float* __restrict__ xA,
                      const int* __restrict__ rpB, const int2* __restrict__ eB, const float* __restrict__ xB,
                      float* __restrict__ out, int nrows) {
    int wave = (int)((blockIdx.x * (long)blockDim.x + threadIdx.x) >> 6);
    int lane = threadIdx.x & 63;
    if (wave >= nrows) return;
    float acc = 0.0f;
    #pragma unroll
    for (int g = 0; g < 2; ++g) {
        const int* rp = g ? rpB : rpA;
        const int2* ee = g ? eB : eA;
        const float* x = g ? xB : xA;
        int s = rp[wave], e = rp[wave + 1];
        for (int j = s; j < e; j += 64) {
            int cnt = e - j; if (cnt > 64) cnt = 64;
            int myc = 0; float myv = 0.0f;
            if (lane < cnt) { int2 p = ee[j + lane]; myc = p.x; myv = __int_as_float(p.y); }
            int t = 0;
            for (; t + 4 <= cnt; t += 4) {
                int c0 = __shfl(myc, t, 64);
                int c1 = __shfl(myc, t + 1, 64);
                int c2 = __shfl(myc, t + 2, 64);
                int c3 = __shfl(myc, t + 3, 64);
                float w0 = __shfl(myv, t, 64);
                float w1 = __shfl(myv, t + 1, 64);
                float w2 = __shfl(myv, t + 2, 64);
                float w3 = __shfl(myv, t + 3, 64);
                float x0 = x[(long)c0 * DDIM + lane];
                float x1 = x[(long)c1 * DDIM + lane];
                float x2 = x[(long)c2 * DDIM + lane];
                float x3 = x[(long)c3 * DDIM + lane];
                acc += w0 * x0; acc += w1 * x1; acc += w2 * x2; acc += w3 * x3;
            }
            for (; t < cnt; ++t) {
                int c = __shfl(myc, t, 64);
                float w = __shfl(myv, t, 64);
                acc += w * x[(long)c * DDIM + lane];
            }
        }
    }
    out[(long)wave * DDIM + lane] = acc;
}

// same as pull2 but only for rows in rowlist; accumulates into acc[b,:]
__global__ void pull2_rows(const int* __restrict__ rpA, const int2* __restrict__ eA, const float* __restrict__ xA,
                           const int* __restrict__ rpB, const int2* __restrict__ eB, const float* __restrict__ xB,
                           const int* __restrict__ rowlist, float* __restrict__ acc, int nlist) {
    int w = (int)((blockIdx.x * (long)blockDim.x + threadIdx.x) >> 6);
    int lane = threadIdx.x & 63;
    if (w >= nlist) return;
    int row = rowlist[w];
    float a = 0.0f;
    #pragma unroll
    for (int g = 0; g < 2; ++g) {
        const int* rp = g ? rpB : rpA;
        const int2* ee = g ? eB : eA;
        const float* x = g ? xB : xA;
        int s = rp[row], e = rp[row + 1];
        for (int j = s; j < e; j += 64) {
            int cnt = e - j; if (cnt > 64) cnt = 64;
            int myc = 0; float myv = 0.0f;
            if (lane < cnt) { int2 p = ee[j + lane]; myc = p.x; myv = __int_as_float(p.y); }
            for (int t = 0; t < cnt; ++t) {
                int c = __shfl(myc, t, 64);
                float wv = __shfl(myv, t, 64);
                a += wv * x[(long)c * DDIM + lane];
            }
        }
    }
    acc[(long)w * DDIM + lane] += a;
}

// ---------- legacy push path (fallback if ws too small) ----------

__global__ void spmm_push(const int* __restrict__ rows, const int* __restrict__ cols,
                          const float* __restrict__ vals, const float* __restrict__ x,
                          float* __restrict__ out, long nnz) {
    long idx = blockIdx.x * (long)blockDim.x + threadIdx.x;
    long stride = (long)gridDim.x * blockDim.x;
    long total = nnz << 6;
    for (; idx < total; idx += stride) {
        long e = idx >> 6;
        int d = (int)(idx & 63);
        int r = rows[e];
        int c = cols[e];
        float v = vals[e];
        atomicAdd(&out[(long)r * DDIM + d], v * x[(long)c * DDIM + d]);
    }
}

static inline int nblk(long threads, long cap) {
    long b = (threads + BLOCK - 1) / BLOCK;
    if (b > cap) b = cap;
    if (b < 1) b = 1;
    return (int)b;
}

extern "C" void kernel_launch(void* const* d_in, const int* in_sizes, int n_in,
                              void* d_out, int out_size, void* d_ws, size_t ws_size,
                              hipStream_t stream) {
    const float* user_emb = (const float*)d_in[0];
    const float* item_emb = (const float*)d_in[1];
    const float* du       = (const float*)d_in[2];
    const float* dv       = (const float*)d_in[3];
    const float* ui_vals  = (const float*)d_in[4];
    const float* uu_vals  = (const float*)d_in[5];
    const float* vv_vals  = (const float*)d_in[6];
    const int*   ui_rows  = (const int*)d_in[7];
    const int*   ui_cols  = (const int*)d_in[8];
    const int*   uu_rows  = (const int*)d_in[9];
    const int*   uu_cols  = (const int*)d_in[10];
    const int*   vv_rows  = (const int*)d_in[11];
    const int*   vv_cols  = (const int*)d_in[12];
    const int*   users    = (const int*)d_in[13];
    const int*   items    = (const int*)d_in[14];

    const int U = in_sizes[2];
    const int I = in_sizes[3];
    const long nnz_ui = in_sizes[4];
    const long nnz_uu = in_sizes[5];
    const long nnz_vv = in_sizes[6];
    const int batch = in_sizes[13];

    const long UD = (long)U * DDIM;
    const long ID = (long)I * DDIM;

    float* gamma = (float*)d_out;

    // ---- workspace carve-up ----
    char* p = (char*)d_ws;
    size_t need = 0;
    #define CARVE(ptr, type, count) type* ptr = (type*)(p + need); need += ((size_t)(count) * sizeof(type) + 255) & ~(size_t)255;
    CARVE(uA, float, UD)
    CARVE(uB, float, UD)
    CARVE(iA, float, ID)
    CARVE(iB, float, ID)
    CARVE(uacc, float, (long)batch * DDIM)
    CARVE(iacc, float, (long)batch * DDIM)
    CARVE(rp_ui, int, U + 1)
    CARVE(rp_uu, int, U + 1)
    CARVE(rp_uiT, int, I + 1)
    CARVE(rp_vv, int, I + 1)
    CARVE(cnt_ui, int, U)       // reused as scatter cursors after scans
    CARVE(cnt_uu, int, U)
    CARVE(cnt_uiT, int, I)
    CARVE(cnt_vv, int, I)
    CARVE(bsum, int, 4 * NBMAX)
    CARVE(e_ui, int2, nnz_ui)
    CARVE(e_uiT, int2, nnz_ui)
    CARVE(e_uu, int2, nnz_uu)
    CARVE(e_vv, int2, nnz_vv)
    #undef CARVE

    int gb = (batch * DDIM + BLOCK - 1) / BLOCK;

    if (need <= ws_size) {
        // ================= CSR pull path =================
        const int nbU = (U + SCAN_CHUNK - 1) / SCAN_CHUNK;   // 98
        const int nbI = (I + SCAN_CHUNK - 1) / SCAN_CHUNK;   // 49

        // zero counters (cnt_* contiguous)
        size_t cnt_span = (size_t)((char*)(cnt_vv + I) - (char*)cnt_ui);
        hipMemsetAsync(cnt_ui, 0, cnt_span, stream);

        hist4<<<nblk(nnz_ui * 2 + nnz_uu + nnz_vv, 4096), BLOCK, 0, stream>>>(
            ui_rows, nnz_ui, cnt_ui,
            uu_rows, nnz_uu, cnt_uu,
            ui_cols, nnz_ui, cnt_uiT,
            vv_rows, nnz_vv, cnt_vv);

        block_sums4<<<2 * nbU + 2 * nbI, 256, 0, stream>>>(
            cnt_ui, U, nbU, cnt_uu, U, nbU, cnt_uiT, I, nbI, cnt_vv, I, nbI, bsum);
        scan_bsums4<<<4, NBMAX, 0, stream>>>(
            bsum, nbU, nbU, nbI, nbI,
            rp_ui, U, rp_uu, U, rp_uiT, I, rp_vv, I);
        scan_chunks4<<<2 * nbU + 2 * nbI, 256, 0, stream>>>(
            cnt_ui, U, nbU, rp_ui,
            cnt_uu, U, nbU, rp_uu,
            cnt_uiT, I, nbI, rp_uiT,
            cnt_vv, I, nbI, rp_vv, bsum);

        // re-zero: cnt_* become scatter cursors
        hipMemsetAsync(cnt_ui, 0, cnt_span, stream);

        scatter_dual<<<nblk(nnz_ui, 4096), BLOCK, 0, stream>>>(
            ui_rows, ui_cols, ui_vals,
            rp_ui, cnt_ui, e_ui, rp_uiT, cnt_uiT, e_uiT, nnz_ui);
        scatter_dual<<<nblk(nnz_uu, 4096), BLOCK, 0, stream>>>(
            uu_rows, uu_cols, uu_vals,
            rp_uu, cnt_uu, e_uu, nullptr, nullptr, nullptr, nnz_uu);
        scatter_dual<<<nblk(nnz_vv, 4096), BLOCK, 0, stream>>>(
            vv_rows, vv_cols, vv_vals,
            rp_vv, cnt_vv, e_vv, nullptr, nullptr, nullptr, nnz_vv);

        // acc init + layer-0 contributions (original embeddings)
        size_t acc_span = (size_t)((char*)(iacc + (long)batch * DDIM) - (char*)uacc);
        hipMemsetAsync(uacc, 0, acc_span, stream);
        gather_add<<<gb, BLOCK, 0, stream>>>(uacc, user_emb, users, batch);
        gather_add<<<gb, BLOCK, 0, stream>>>(iacc, item_emb, items, batch);

        // layer-0 update: cur = emb0 * (1 + d)
        first_comb4<<<nblk(UD / 4, 4096), BLOCK, 0, stream>>>(
            (float4*)uA, (const float4*)user_emb, du, UD / 4);
        first_comb4<<<nblk(ID / 4, 4096), BLOCK, 0, stream>>>(
            (float4*)iA, (const float4*)item_emb, dv, ID / 4);

        float* ucur = uA; float* unext = uB;
        float* icur = iA; float* inext = iB;

        int ub = (U * 64 + BLOCK - 1) / BLOCK;
        int ib = (I * 64 + BLOCK - 1) / BLOCK;

        for (int layer = 0; layer < 3; ++layer) {
            if (layer > 0) {   // layer-0 update already fused into first_comb4
                add_scaled4<<<nblk(UD / 4, 4096), BLOCK, 0, stream>>>(
                    (float4*)ucur, (const float4*)user_emb, du, UD / 4);
                add_scaled4<<<nblk(ID / 4, 4096), BLOCK, 0, stream>>>(
                    (float4*)icur, (const float4*)item_emb, dv, ID / 4);
            }

            // users_next = A_ui @ icur + A_uu @ ucur
            pull2<<<ub, BLOCK, 0, stream>>>(rp_ui, e_ui, icur,
                                            rp_uu, e_uu, ucur, unext, U);
            gather_add<<<gb, BLOCK, 0, stream>>>(uacc, unext, users, batch);

            if (layer < 2) {
                // items_next = A_ui^T @ unext + A_vv @ icur
                pull2<<<ib, BLOCK, 0, stream>>>(rp_uiT, e_uiT, unext,
                                                rp_vv, e_vv, icur, inext, I);
                gather_add<<<gb, BLOCK, 0, stream>>>(iacc, inext, items, batch);
            } else {
                // last layer: item embedding only needed at sampled rows
                pull2_rows<<<gb, BLOCK, 0, stream>>>(rp_uiT, e_uiT, unext,
                                                     rp_vv, e_vv, icur,
                                                     items, iacc, batch);
            }

            float* t;
            t = ucur; ucur = unext; unext = t;
            t = icur; icur = inext; inext = t;
        }

        final_gamma<<<gb, BLOCK, 0, stream>>>(uacc, iacc, gamma, batch);
    } else {
        // ================= fallback: push-atomic path =================
        float* ws = (float*)d_ws;
        float* fuA   = ws;
        float* fuB   = fuA + UD;
        float* fiA   = fuB + UD;
        float* fiB   = fiA + ID;
        float* fuacc = fiB + ID;
        float* fiacc = fuacc + (long)batch * DDIM;

        hipMemsetAsync(fuacc, 0, (size_t)batch * DDIM * sizeof(float) * 2, stream);
        gather_add<<<gb, BLOCK, 0, stream>>>(fuacc, user_emb, users, batch);
        gather_add<<<gb, BLOCK, 0, stream>>>(fiacc, item_emb, items, batch);

        first_comb4<<<nblk(UD / 4, 4096), BLOCK, 0, stream>>>(
            (float4*)fuA, (const float4*)user_emb, du, UD / 4);
        first_comb4<<<nblk(ID / 4, 4096), BLOCK, 0, stream>>>(
            (float4*)fiA, (const float4*)item_emb, dv, ID / 4);

        float* ucur = fuA; float* unext = fuB;
        float* icur = fiA; float* inext = fiB;

        for (int layer = 0; layer < 3; ++layer) {
            if (layer > 0) {
                add_scaled4<<<nblk(UD / 4, 4096), BLOCK, 0, stream>>>(
                    (float4*)ucur, (const float4*)user_emb, du, UD / 4);
                add_scaled4<<<nblk(ID / 4, 4096), BLOCK, 0, stream>>>(
                    (float4*)icur, (const float4*)item_emb, dv, ID / 4);
            }

            hipMemsetAsync(unext, 0, UD * sizeof(float), stream);
            spmm_push<<<nblk(nnz_ui << 6, 16384), BLOCK, 0, stream>>>(
                ui_rows, ui_cols, ui_vals, icur, unext, nnz_ui);
            spmm_push<<<nblk(nnz_uu << 6, 16384), BLOCK, 0, stream>>>(
                uu_rows, uu_cols, uu_vals, ucur, unext, nnz_uu);

            hipMemsetAsync(inext, 0, ID * sizeof(float), stream);
            spmm_push<<<nblk(nnz_vv << 6, 16384), BLOCK, 0, stream>>>(
                vv_rows, vv_cols, vv_vals, icur, inext, nnz_vv);
            spmm_push<<<nblk(nnz_ui << 6, 16384), BLOCK, 0, stream>>>(
                ui_cols, ui_rows, ui_vals, unext, inext, nnz_ui);

            gather_add<<<gb, BLOCK, 0, stream>>>(fuacc, unext, users, batch);
            gather_add<<<gb, BLOCK, 0, stream>>>(fiacc, inext, items, batch);

            float* t;
            t = ucur; ucur = unext; unext = t;
            t = icur; icur = inext; inext = t;
        }

        final_gamma<<<gb, BLOCK, 0, stream>>>(fuacc, fiacc, gamma, batch);
    }
}

// Round 4
// 1289.178 us; speedup vs baseline: 3.0662x; 1.0280x over previous
//
#include <hip/hip_runtime.h>

#define BLOCK 256
#define DDIM 64
#define SCAN_CHUNK 2048   // 256 threads * 8 elements
#define NBMAX 128         // max scan chunks per segment (U=200K -> 98)

// ---------- elementwise / small kernels ----------

// dst = emb0 * (1 + scale[row])   (layer-0 fused copy+add)
__global__ void first_comb4(float4* __restrict__ dst, const float4* __restrict__ emb0,
                            const float* __restrict__ scale, long n4) {
    long idx = blockIdx.x * (long)blockDim.x + threadIdx.x;
    long stride = (long)gridDim.x * blockDim.x;
    for (; idx < n4; idx += stride) {
        float s = 1.0f + scale[idx >> 4];
        float4 e = emb0[idx];
        e.x *= s; e.y *= s; e.z *= s; e.w *= s;
        dst[idx] = e;
    }
}

// cur += scale[row] * emb0
__global__ void add_scaled4(float4* __restrict__ cur, const float4* __restrict__ emb0,
                            const float* __restrict__ scale, long n4) {
    long idx = blockIdx.x * (long)blockDim.x + threadIdx.x;
    long stride = (long)gridDim.x * blockDim.x;
    for (; idx < n4; idx += stride) {
        float s = scale[idx >> 4];
        float4 e = emb0[idx];
        float4 c = cur[idx];
        c.x += s * e.x; c.y += s * e.y; c.z += s * e.z; c.w += s * e.w;
        cur[idx] = c;
    }
}

__global__ void gather_add(float* __restrict__ acc, const float* __restrict__ emb,
                           const int* __restrict__ idxs, int batch) {
    int t = blockIdx.x * blockDim.x + threadIdx.x;
    if (t >= batch * DDIM) return;
    int b = t >> 6;
    acc[t] += emb[(long)idxs[b] * DDIM + (t & 63)];
}

__global__ void final_gamma(const float* __restrict__ uacc, const float* __restrict__ iacc,
                            float* __restrict__ out, int batch) {
    int t = blockIdx.x * blockDim.x + threadIdx.x;
    if (t >= batch * DDIM) return;
    int b = t >> 6;
    float v = uacc[t] * iacc[t];
    #pragma unroll
    for (int off = 32; off; off >>= 1) v += __shfl_down(v, off, 64);
    if ((threadIdx.x & 63) == 0) out[b] = v * (1.0f / 16.0f);
}

// ---------- CSR build (fused) ----------

// 4 histograms in one kernel
__global__ void hist4(const int* __restrict__ a0, long n0, int* __restrict__ c0,
                      const int* __restrict__ a1, long n1, int* __restrict__ c1,
                      const int* __restrict__ a2, long n2, int* __restrict__ c2,
                      const int* __restrict__ a3, long n3, int* __restrict__ c3) {
    long idx = blockIdx.x * (long)blockDim.x + threadIdx.x;
    long stride = (long)gridDim.x * blockDim.x;
    long t01 = n0 + n1, t012 = n0 + n1 + n2, total = t012 + n3;
    for (; idx < total; idx += stride) {
        if (idx < n0)        atomicAdd(&c0[a0[idx]], 1);
        else if (idx < t01)  atomicAdd(&c1[a1[idx - n0]], 1);
        else if (idx < t012) atomicAdd(&c2[a2[idx - t01]], 1);
        else                 atomicAdd(&c3[a3[idx - t012]], 1);
    }
}

// segmented block sums over 4 count arrays
__global__ void block_sums4(const int* __restrict__ i0, int n0, int nb0,
                            const int* __restrict__ i1, int n1, int nb1,
                            const int* __restrict__ i2, int n2, int nb2,
                            const int* __restrict__ i3, int n3, int nb3,
                            int* __restrict__ bsum /* [4][NBMAX] */) {
    __shared__ int sdata[256];
    int b = blockIdx.x, seg, lb; const int* in; int n;
    if (b < nb0)                 { seg = 0; lb = b;                 in = i0; n = n0; }
    else if (b < nb0 + nb1)      { seg = 1; lb = b - nb0;           in = i1; n = n1; }
    else if (b < nb0 + nb1 + nb2){ seg = 2; lb = b - nb0 - nb1;     in = i2; n = n2; }
    else                         { seg = 3; lb = b - nb0 - nb1 - nb2; in = i3; n = n3; }
    int base = lb * SCAN_CHUNK;
    int t = threadIdx.x;
    int s = 0;
    #pragma unroll
    for (int k = 0; k < 8; ++k) {
        int i = base + t * 8 + k;
        if (i < n) s += in[i];
    }
    sdata[t] = s;
    __syncthreads();
    for (int off = 128; off; off >>= 1) {
        if (t < off) sdata[t] += sdata[t + off];
        __syncthreads();
    }
    if (t == 0) bsum[seg * NBMAX + lb] = sdata[0];
}

// 4 blocks; block `seg` exclusive-scans bsum[seg][0..nb) in place, total -> rp[n]
__global__ void scan_bsums4(int* __restrict__ bsum,
                            int nb0, int nb1, int nb2, int nb3,
                            int* __restrict__ rp0, int m0, int* __restrict__ rp1, int m1,
                            int* __restrict__ rp2, int m2, int* __restrict__ rp3, int m3) {
    __shared__ int sdata[NBMAX];
    int seg = blockIdx.x;
    int nb = seg == 0 ? nb0 : seg == 1 ? nb1 : seg == 2 ? nb2 : nb3;
    int* rp = seg == 0 ? rp0 : seg == 1 ? rp1 : seg == 2 ? rp2 : rp3;
    int m  = seg == 0 ? m0  : seg == 1 ? m1  : seg == 2 ? m2  : m3;
    int t = threadIdx.x;                 // blockDim == NBMAX
    int v = (t < nb) ? bsum[seg * NBMAX + t] : 0;
    sdata[t] = v;
    __syncthreads();
    for (int off = 1; off < NBMAX; off <<= 1) {
        int add = (t >= off) ? sdata[t - off] : 0;
        __syncthreads();
        sdata[t] += add;
        __syncthreads();
    }
    if (t < nb) bsum[seg * NBMAX + t] = sdata[t] - v;     // exclusive
    if (t == NBMAX - 1) rp[m] = sdata[NBMAX - 1];         // grand total = nnz
}

// segmented chunk scan: rp[i] = exclusive scan of cnt
__global__ void scan_chunks4(const int* __restrict__ i0, int n0, int nb0, int* __restrict__ r0,
                             const int* __restrict__ i1, int n1, int nb1, int* __restrict__ r1,
                             const int* __restrict__ i2, int n2, int nb2, int* __restrict__ r2,
                             const int* __restrict__ i3, int n3, int nb3, int* __restrict__ r3,
                             const int* __restrict__ bsum) {
    __shared__ int sdata[256];
    int b = blockIdx.x, seg, lb; const int* in; int n; int* out;
    if (b < nb0)                 { seg = 0; lb = b;                 in = i0; n = n0; out = r0; }
    else if (b < nb0 + nb1)      { seg = 1; lb = b - nb0;           in = i1; n = n1; out = r1; }
    else if (b < nb0 + nb1 + nb2){ seg = 2; lb = b - nb0 - nb1;     in = i2; n = n2; out = r2; }
    else                         { seg = 3; lb = b - nb0 - nb1 - nb2; in = i3; n = n3; out = r3; }
    int base = lb * SCAN_CHUNK;
    int t = threadIdx.x;
    int loc[8];
    int s = 0;
    #pragma unroll
    for (int k = 0; k < 8; ++k) {
        int i = base + t * 8 + k;
        int v = (i < n) ? in[i] : 0;
        loc[k] = s;
        s += v;
    }
    sdata[t] = s;
    __syncthreads();
    for (int off = 1; off < 256; off <<= 1) {
        int add = (t >= off) ? sdata[t - off] : 0;
        __syncthreads();
        sdata[t] += add;
        __syncthreads();
    }
    int texcl = sdata[t] - s + bsum[seg * NBMAX + lb];
    #pragma unroll
    for (int k = 0; k < 8; ++k) {
        int i = base + t * 8 + k;
        if (i < n) out[i] = texcl + loc[k];
    }
}

// scatter edges into packed (col,val) CSR; optionally also the transpose
__global__ void scatter_dual(const int* __restrict__ rows, const int* __restrict__ cols,
                             const float* __restrict__ vals,
                             const int* __restrict__ rpA, int* __restrict__ curA, int2* __restrict__ eA,
                             const int* __restrict__ rpB, int* __restrict__ curB, int2* __restrict__ eB,
                             long nnz) {
    long idx = blockIdx.x * (long)blockDim.x + threadIdx.x;
    long stride = (long)gridDim.x * blockDim.x;
    for (; idx < nnz; idx += stride) {
        int r = rows[idx];
        int c = cols[idx];
        int vb = __float_as_int(vals[idx]);
        int pa = rpA[r] + atomicAdd(&curA[r], 1);
        eA[pa] = make_int2(c, vb);
        if (eB) {
            int pb = rpB[c] + atomicAdd(&curB[c], 1);
            eB[pb] = make_int2(r, vb);
        }
    }
}

// ---------- pull-style fused SpMM (packed edges, 16-lane float4 groups) ----------

// Per-wave partial for one row of one CSR: 4 groups of 16 lanes, each group
// handles one edge per step; lane l16 accumulates dims [l16*4, l16*4+4).
__device__ __forceinline__ float4 row_part(const int* __restrict__ rp,
                                           const int2* __restrict__ ee,
                                           const float* __restrict__ x,
                                           int row, int lane) {
    const int l16 = lane & 15;
    const int g = lane >> 4;
    const float4* x4 = (const float4*)x;
    float4 acc = make_float4(0.f, 0.f, 0.f, 0.f);
    int s = rp[row], e = rp[row + 1];
    for (int j = s; j < e; j += 64) {
        int cnt = e - j; if (cnt > 64) cnt = 64;
        int myc = 0; float myv = 0.0f;
        if (lane < cnt) { int2 pr = ee[j + lane]; myc = pr.x; myv = __int_as_float(pr.y); }
        int steps = (cnt + 3) >> 2;
        #pragma unroll 4
        for (int st = 0; st < steps; ++st) {
            int t = st * 4 + g;
            int c = __shfl(myc, t, 64);
            float w = __shfl(myv, t, 64);
            bool ok = t < cnt;
            c = ok ? c : 0;
            w = ok ? w : 0.0f;
            float4 xv = x4[(long)c * 16 + l16];
            acc.x += w * xv.x; acc.y += w * xv.y; acc.z += w * xv.z; acc.w += w * xv.w;
        }
    }
    return acc;
}

__device__ __forceinline__ float4 group_reduce(float4 a) {
    a.x += __shfl_xor(a.x, 16, 64); a.y += __shfl_xor(a.y, 16, 64);
    a.z += __shfl_xor(a.z, 16, 64); a.w += __shfl_xor(a.w, 16, 64);
    a.x += __shfl_xor(a.x, 32, 64); a.y += __shfl_xor(a.y, 32, 64);
    a.z += __shfl_xor(a.z, 32, 64); a.w += __shfl_xor(a.w, 32, 64);
    return a;
}

__global__ void pull2(const int* __restrict__ rpA, const int2* __restrict__ eA, const float* __restrict__ xA,
                      const int* __restrict__ rpB, const int2* __restrict__ eB, const float* __restrict__ xB,
                      float* __restrict__ out, int nrows) {
    int wave = (int)((blockIdx.x * (long)blockDim.x + threadIdx.x) >> 6);
    int lane = threadIdx.x & 63;
    if (wave >= nrows) return;
    float4 a = row_part(rpA, eA, xA, wave, lane);
    float4 b = row_part(rpB, eB, xB, wave, lane);
    a.x += b.x; a.y += b.y; a.z += b.z; a.w += b.w;
    a = group_reduce(a);
    if (lane < 16) ((float4*)out)[(long)wave * 16 + lane] = a;
}

// same but only for rows in rowlist; accumulates into acc[b,:]
__global__ void pull2_rows(const int* __restrict__ rpA, const int2* __restrict__ eA, const float* __restrict__ xA,
                           const int* __restrict__ rpB, const int2* __restrict__ eB, const float* __restrict__ xB,
                           const int* __restrict__ rowlist, float* __restrict__ acc, int nlist) {
    int w = (int)((blockIdx.x * (long)blockDim.x + threadIdx.x) >> 6);
    int lane = threadIdx.x & 63;
    if (w >= nlist) return;
    int row = rowlist[w];
    float4 a = row_part(rpA, eA, xA, row, lane);
    float4 b = row_part(rpB, eB, xB, row, lane);
    a.x += b.x; a.y += b.y; a.z += b.z; a.w += b.w;
    a = group_reduce(a);
    if (lane < 16) {
        float4* acc4 = (float4*)acc;
        float4 cur = acc4[(long)w * 16 + lane];
        cur.x += a.x; cur.y += a.y; cur.z += a.z; cur.w += a.w;
        acc4[(long)w * 16 + lane] = cur;
    }
}

// ---------- legacy push path (fallback if ws too small) ----------

__global__ void spmm_push(const int* __restrict__ rows, const int* __restrict__ cols,
                          const float* __restrict__ vals, const float* __restrict__ x,
                          float* __restrict__ out, long nnz) {
    long idx = blockIdx.x * (long)blockDim.x + threadIdx.x;
    long stride = (long)gridDim.x * blockDim.x;
    long total = nnz << 6;
    for (; idx < total; idx += stride) {
        long e = idx >> 6;
        int d = (int)(idx & 63);
        int r = rows[e];
        int c = cols[e];
        float v = vals[e];
        atomicAdd(&out[(long)r * DDIM + d], v * x[(long)c * DDIM + d]);
    }
}

static inline int nblk(long threads, long cap) {
    long b = (threads + BLOCK - 1) / BLOCK;
    if (b > cap) b = cap;
    if (b < 1) b = 1;
    return (int)b;
}

extern "C" void kernel_launch(void* const* d_in, const int* in_sizes, int n_in,
                              void* d_out, int out_size, void* d_ws, size_t ws_size,
                              hipStream_t stream) {
    const float* user_emb = (const float*)d_in[0];
    const float* item_emb = (const float*)d_in[1];
    const float* du       = (const float*)d_in[2];
    const float* dv       = (const float*)d_in[3];
    const float* ui_vals  = (const float*)d_in[4];
    const float* uu_vals  = (const float*)d_in[5];
    const float* vv_vals  = (const float*)d_in[6];
    const int*   ui_rows  = (const int*)d_in[7];
    const int*   ui_cols  = (const int*)d_in[8];
    const int*   uu_rows  = (const int*)d_in[9];
    const int*   uu_cols  = (const int*)d_in[10];
    const int*   vv_rows  = (const int*)d_in[11];
    const int*   vv_cols  = (const int*)d_in[12];
    const int*   users    = (const int*)d_in[13];
    const int*   items    = (const int*)d_in[14];

    const int U = in_sizes[2];
    const int I = in_sizes[3];
    const long nnz_ui = in_sizes[4];
    const long nnz_uu = in_sizes[5];
    const long nnz_vv = in_sizes[6];
    const int batch = in_sizes[13];

    const long UD = (long)U * DDIM;
    const long ID = (long)I * DDIM;

    float* gamma = (float*)d_out;

    // ---- workspace carve-up ----
    char* p = (char*)d_ws;
    size_t need = 0;
    #define CARVE(ptr, type, count) type* ptr = (type*)(p + need); need += ((size_t)(count) * sizeof(type) + 255) & ~(size_t)255;
    CARVE(uA, float, UD)
    CARVE(uB, float, UD)
    CARVE(iA, float, ID)
    CARVE(iB, float, ID)
    CARVE(uacc, float, (long)batch * DDIM)
    CARVE(iacc, float, (long)batch * DDIM)
    CARVE(rp_ui, int, U + 1)
    CARVE(rp_uu, int, U + 1)
    CARVE(rp_uiT, int, I + 1)
    CARVE(rp_vv, int, I + 1)
    CARVE(cnt_ui, int, U)       // reused as scatter cursors after scans
    CARVE(cnt_uu, int, U)
    CARVE(cnt_uiT, int, I)
    CARVE(cnt_vv, int, I)
    CARVE(bsum, int, 4 * NBMAX)
    CARVE(e_ui, int2, nnz_ui)
    CARVE(e_uiT, int2, nnz_ui)
    CARVE(e_uu, int2, nnz_uu)
    CARVE(e_vv, int2, nnz_vv)
    #undef CARVE

    int gb = (batch * DDIM + BLOCK - 1) / BLOCK;

    if (need <= ws_size) {
        // ================= CSR pull path =================
        const int nbU = (U + SCAN_CHUNK - 1) / SCAN_CHUNK;   // 98
        const int nbI = (I + SCAN_CHUNK - 1) / SCAN_CHUNK;   // 49

        // zero counters (cnt_* contiguous)
        size_t cnt_span = (size_t)((char*)(cnt_vv + I) - (char*)cnt_ui);
        hipMemsetAsync(cnt_ui, 0, cnt_span, stream);

        hist4<<<nblk(nnz_ui * 2 + nnz_uu + nnz_vv, 4096), BLOCK, 0, stream>>>(
            ui_rows, nnz_ui, cnt_ui,
            uu_rows, nnz_uu, cnt_uu,
            ui_cols, nnz_ui, cnt_uiT,
            vv_rows, nnz_vv, cnt_vv);

        block_sums4<<<2 * nbU + 2 * nbI, 256, 0, stream>>>(
            cnt_ui, U, nbU, cnt_uu, U, nbU, cnt_uiT, I, nbI, cnt_vv, I, nbI, bsum);
        scan_bsums4<<<4, NBMAX, 0, stream>>>(
            bsum, nbU, nbU, nbI, nbI,
            rp_ui, U, rp_uu, U, rp_uiT, I, rp_vv, I);
        scan_chunks4<<<2 * nbU + 2 * nbI, 256, 0, stream>>>(
            cnt_ui, U, nbU, rp_ui,
            cnt_uu, U, nbU, rp_uu,
            cnt_uiT, I, nbI, rp_uiT,
            cnt_vv, I, nbI, rp_vv, bsum);

        // re-zero: cnt_* become scatter cursors
        hipMemsetAsync(cnt_ui, 0, cnt_span, stream);

        scatter_dual<<<nblk(nnz_ui, 4096), BLOCK, 0, stream>>>(
            ui_rows, ui_cols, ui_vals,
            rp_ui, cnt_ui, e_ui, rp_uiT, cnt_uiT, e_uiT, nnz_ui);
        scatter_dual<<<nblk(nnz_uu, 4096), BLOCK, 0, stream>>>(
            uu_rows, uu_cols, uu_vals,
            rp_uu, cnt_uu, e_uu, nullptr, nullptr, nullptr, nnz_uu);
        scatter_dual<<<nblk(nnz_vv, 4096), BLOCK, 0, stream>>>(
            vv_rows, vv_cols, vv_vals,
            rp_vv, cnt_vv, e_vv, nullptr, nullptr, nullptr, nnz_vv);

        // acc init + layer-0 contributions (original embeddings)
        size_t acc_span = (size_t)((char*)(iacc + (long)batch * DDIM) - (char*)uacc);
        hipMemsetAsync(uacc, 0, acc_span, stream);
        gather_add<<<gb, BLOCK, 0, stream>>>(uacc, user_emb, users, batch);
        gather_add<<<gb, BLOCK, 0, stream>>>(iacc, item_emb, items, batch);

        // layer-0 update: cur = emb0 * (1 + d)
        first_comb4<<<nblk(UD / 4, 4096), BLOCK, 0, stream>>>(
            (float4*)uA, (const float4*)user_emb, du, UD / 4);
        first_comb4<<<nblk(ID / 4, 4096), BLOCK, 0, stream>>>(
            (float4*)iA, (const float4*)item_emb, dv, ID / 4);

        float* ucur = uA; float* unext = uB;
        float* icur = iA; float* inext = iB;

        int ub = (int)((UD + BLOCK - 1) / BLOCK);   // U*64 threads = wave per row
        int ib = (int)((ID + BLOCK - 1) / BLOCK);

        for (int layer = 0; layer < 3; ++layer) {
            if (layer > 0) {   // layer-0 update already fused into first_comb4
                add_scaled4<<<nblk(UD / 4, 4096), BLOCK, 0, stream>>>(
                    (float4*)ucur, (const float4*)user_emb, du, UD / 4);
                add_scaled4<<<nblk(ID / 4, 4096), BLOCK, 0, stream>>>(
                    (float4*)icur, (const float4*)item_emb, dv, ID / 4);
            }

            // users_next = A_ui @ icur + A_uu @ ucur
            pull2<<<ub, BLOCK, 0, stream>>>(rp_ui, e_ui, icur,
                                            rp_uu, e_uu, ucur, unext, U);
            gather_add<<<gb, BLOCK, 0, stream>>>(uacc, unext, users, batch);

            if (layer < 2) {
                // items_next = A_ui^T @ unext + A_vv @ icur
                pull2<<<ib, BLOCK, 0, stream>>>(rp_uiT, e_uiT, unext,
                                                rp_vv, e_vv, icur, inext, I);
                gather_add<<<gb, BLOCK, 0, stream>>>(iacc, inext, items, batch);
            } else {
                // last layer: item embedding only needed at sampled rows
                pull2_rows<<<gb, BLOCK, 0, stream>>>(rp_uiT, e_uiT, unext,
                                                     rp_vv, e_vv, icur,
                                                     items, iacc, batch);
            }

            float* t;
            t = ucur; ucur = unext; unext = t;
            t = icur; icur = inext; inext = t;
        }

        final_gamma<<<gb, BLOCK, 0, stream>>>(uacc, iacc, gamma, batch);
    } else {
        // ================= fallback: push-atomic path =================
        float* ws = (float*)d_ws;
        float* fuA   = ws;
        float* fuB   = fuA + UD;
        float* fiA   = fuB + UD;
        float* fiB   = fiA + ID;
        float* fuacc = fiB + ID;
        float* fiacc = fuacc + (long)batch * DDIM;

        hipMemsetAsync(fuacc, 0, (size_t)batch * DDIM * sizeof(float) * 2, stream);
        gather_add<<<gb, BLOCK, 0, stream>>>(fuacc, user_emb, users, batch);
        gather_add<<<gb, BLOCK, 0, stream>>>(fiacc, item_emb, items, batch);

        first_comb4<<<nblk(UD / 4, 4096), BLOCK, 0, stream>>>(
            (float4*)fuA, (const float4*)user_emb, du, UD / 4);
        first_comb4<<<nblk(ID / 4, 4096), BLOCK, 0, stream>>>(
            (float4*)fiA, (const float4*)item_emb, dv, ID / 4);

        float* ucur = fuA; float* unext = fuB;
        float* icur = fiA; float* inext = fiB;

        for (int layer = 0; layer < 3; ++layer) {
            if (layer > 0) {
                add_scaled4<<<nblk(UD / 4, 4096), BLOCK, 0, stream>>>(
                    (float4*)ucur, (const float4*)user_emb, du, UD / 4);
                add_scaled4<<<nblk(ID / 4, 4096), BLOCK, 0, stream>>>(
                    (float4*)icur, (const float4*)item_emb, dv, ID / 4);
            }

            hipMemsetAsync(unext, 0, UD * sizeof(float), stream);
            spmm_push<<<nblk(nnz_ui << 6, 16384), BLOCK, 0, stream>>>(
                ui_rows, ui_cols, ui_vals, icur, unext, nnz_ui);
            spmm_push<<<nblk(nnz_uu << 6, 16384), BLOCK, 0, stream>>>(
                uu_rows, uu_cols, uu_vals, ucur, unext, nnz_uu);

            hipMemsetAsync(inext, 0, ID * sizeof(float), stream);
            spmm_push<<<nblk(nnz_vv << 6, 16384), BLOCK, 0, stream>>>(
                vv_rows, vv_cols, vv_vals, icur, inext, nnz_vv);
            spmm_push<<<nblk(nnz_ui << 6, 16384), BLOCK, 0, stream>>>(
                ui_cols, ui_rows, ui_vals, unext, inext, nnz_ui);

            gather_add<<<gb, BLOCK, 0, stream>>>(fuacc, unext, users, batch);
            gather_add<<<gb, BLOCK, 0, stream>>>(fiacc, inext, items, batch);

            float* t;
            t = ucur; ucur = unext; unext = t;
            t = icur; icur = inext; inext = t;
        }

        final_gamma<<<gb, BLOCK, 0, stream>>>(fuacc, fiacc, gamma, batch);
    }
}